// Round 1
// baseline (313.203 us; speedup 1.0000x reference)
//
#include <hip/hip_runtime.h>
#include <hip/hip_fp16.h>

// LightGCN, atomic-free COMPACT CSR build + fp16 gather layers.
//  pass1 (1172 blocks, EPB=1024): int4 edge loads, LDS bucket histograms (293 buckets of 512
//         nodes), per-(block,bucket) run reservation, scatter to bucket streams.
//         (EPB 4096->1024: 293 blocks was 1 block/CU = 1 wave/SIMD, latency-starved.)
//  pass2 (586 blocks): col-blocks: LDS hist -> scan -> compact CSR + packed(ptr,cnt) + inv_col;
//         row-blocks: LDS hist -> inv_row.  (y0 init is a separate full-grid kernel — NOT fused;
//         fusing it in r7 serialized 9.6 MB of streaming through 147 blocks and cost 50 µs.)
//  layers: one wave/node. Gather is 16 B/lane (8 lanes per 128-B fp16 row), so ONE load
//         instruction covers 8 edges (1 KB in flight) — avg degree 8 => most nodes take a
//         single gather round instead of ceil(cnt/4)=2-3 dependent rounds (r0 was
//         latency-bound: HBM 32%, VALUBusy 36%). Cross-edge reduce = 3x shfl_xor (8/16/32).
//         Epilogue out/emb read hoisted ABOVE the gather loop (independent -> overlaps).

constexpr int NUM_USERS = 100000;
constexpr int NUM_ITEMS = 50000;
constexpr int N_NODES   = NUM_USERS + NUM_ITEMS;   // 150000
constexpr int EMBED_DIM = 64;
constexpr int NUM_EDGES = 1200000;
constexpr int SHIFT = 9;                           // coarse bucket = node >> 9
constexpr int BSZ   = 1 << SHIFT;                  // 512 nodes per bucket
constexpr int NBUCK = (N_NODES + BSZ - 1) >> SHIFT;            // 293
constexpr int CAPC  = 4480;                        // bucket capacity (Poisson mean 4096, sigma 64)
constexpr int EPB   = 1024;                        // edges per pass-1 block (256 thr x 1 int4)
constexpr int P1_BLOCKS = (NUM_EDGES + EPB - 1) / EPB;         // 1172

// ---- pass 1: LDS-aggregated binning (int4 = 4 edges per thread-iter) ----
__global__ void __launch_bounds__(256)
pass1_bin(const int4* __restrict__ row4, const int4* __restrict__ col4,
          int* __restrict__ gcur_c, int* __restrict__ gcur_r,
          unsigned int* __restrict__ binned_c, unsigned short* __restrict__ binned_r) {
    __shared__ int hist_c[NBUCK], hist_r[NBUCK], cur_c[NBUCK], cur_r[NBUCK];
    int t = threadIdx.x;
    for (int i = t; i < NBUCK; i += 256) { hist_c[i] = 0; hist_r[i] = 0; }
    __syncthreads();
    int base4 = blockIdx.x * (EPB / 4);
    constexpr int NV = NUM_EDGES / 4;
    // phase A: per-block bucket counts
    {
        int v = base4 + t;
        if (v < NV) {
            int4 c = col4[v];
            atomicAdd(&hist_c[c.x >> SHIFT], 1);
            atomicAdd(&hist_c[c.y >> SHIFT], 1);
            atomicAdd(&hist_c[c.z >> SHIFT], 1);
            atomicAdd(&hist_c[c.w >> SHIFT], 1);
            int4 r = row4[v];
            atomicAdd(&hist_r[r.x >> SHIFT], 1);
            atomicAdd(&hist_r[r.y >> SHIFT], 1);
            atomicAdd(&hist_r[r.z >> SHIFT], 1);
            atomicAdd(&hist_r[r.w >> SHIFT], 1);
        }
    }
    __syncthreads();
    // phase B: reserve contiguous runs (one global atomic per block x bucket)
    for (int i = t; i < NBUCK; i += 256) {
        cur_c[i] = atomicAdd(&gcur_c[i], hist_c[i]);
        cur_r[i] = atomicAdd(&gcur_r[i], hist_r[i]);
    }
    __syncthreads();
    // phase C: scatter into bucket streams
    {
        int v = base4 + t;
        if (v < NV) {
            int4 c = col4[v];
            int4 r = row4[v];
            int cc[4] = {c.x, c.y, c.z, c.w};
            int rr[4] = {r.x, r.y, r.z, r.w};
#pragma unroll
            for (int q = 0; q < 4; ++q) {
                int dc = cc[q] >> SHIFT;
                int sc = atomicAdd(&cur_c[dc], 1);
                if (sc < CAPC)
                    binned_c[dc * CAPC + sc] =
                        ((unsigned)(cc[q] & (BSZ - 1)) << 18) | (unsigned)rr[q];
                int dr = rr[q] >> SHIFT;
                int sr = atomicAdd(&cur_r[dr], 1);
                if (sr < CAPC)
                    binned_r[dr * CAPC + sr] = (unsigned short)(rr[q] & (BSZ - 1));
            }
        }
    }
}

// ---- pass 2 ----
// blocks 0..292: compact CSR for col-bucket b + packed(ptr,cnt) + inv_col
// blocks 293..585: row histogram -> inv_row
__global__ void __launch_bounds__(256)
pass2_place(const int* __restrict__ gcur_c, const int* __restrict__ gcur_r,
            const unsigned int* __restrict__ binned_c, const unsigned short* __restrict__ binned_r,
            int* __restrict__ sorted_idx, int* __restrict__ packed_pc,
            float* __restrict__ inv_col, float* __restrict__ inv_row) {
    __shared__ int hist[BSZ];
    __shared__ int partial[256];
    int t = threadIdx.x;
    hist[t] = 0; hist[t + 256] = 0;
    __syncthreads();
    int b = blockIdx.x;
    if (b < NBUCK) {
        int n = gcur_c[b]; if (n > CAPC) n = CAPC;
        const unsigned int* src = binned_c + b * CAPC;
        // local histogram
        for (int i = t; i < n; i += 256) atomicAdd(&hist[src[i] >> 18], 1);
        // bucket base = sum of gcur_c[0..b)
        int s = 0;
        for (int i = t; i < b; i += 256) s += gcur_c[i];
        partial[t] = s;
        __syncthreads();
        for (int off = 128; off > 0; off >>= 1) {
            if (t < off) partial[t] += partial[t + off];
            __syncthreads();
        }
        int bucket_base = partial[0];
        __syncthreads();
        // exclusive scan of hist[0..511] (2 entries per thread)
        int v0 = hist[t * 2], v1 = hist[t * 2 + 1];
        int sum = v0 + v1;
        partial[t] = sum; __syncthreads();
        for (int off = 1; off < 256; off <<= 1) {
            int tv = (t >= off) ? partial[t - off] : 0;
            __syncthreads();
            partial[t] += tv;
            __syncthreads();
        }
        int excl = partial[t] - sum;
        int o0 = excl, o1 = excl + v0;
        hist[t * 2] = o0; hist[t * 2 + 1] = o1;
        // packed(ptr,cnt) + inv_col  (cnt < 128; ptr < 2^21)
        int c0 = (b << SHIFT) | (t * 2);
        if (c0 < N_NODES) {
            packed_pc[c0] = ((bucket_base + o0) << 7) | v0;
            inv_col[c0] = (v0 > 0) ? rsqrtf((float)v0) : 0.0f;
        }
        int c1 = c0 + 1;
        if (c1 < N_NODES) {
            packed_pc[c1] = ((bucket_base + o1) << 7) | v1;
            inv_col[c1] = (v1 > 0) ? rsqrtf((float)v1) : 0.0f;
        }
        __syncthreads();
        // compact placement via LDS cursors
        for (int i = t; i < n; i += 256) {
            unsigned int w = src[i];
            int lc = w >> 18;
            int r  = (int)(w & 0x3FFFFu);
            int slot = atomicAdd(&hist[lc], 1);
            sorted_idx[bucket_base + slot] = r;
        }
    } else {
        int bb = b - NBUCK;
        int n = gcur_r[bb]; if (n > CAPC) n = CAPC;
        const unsigned short* src = binned_r + bb * CAPC;
        for (int i = t; i < n; i += 256) atomicAdd(&hist[src[i]], 1);
        __syncthreads();
        int c0 = (bb << SHIFT) | (t * 2);
        int v0 = hist[t * 2], v1 = hist[t * 2 + 1];
        if (c0 < N_NODES)     inv_row[c0] = (v0 > 0) ? rsqrtf((float)v0) : 0.0f;
        if (c0 + 1 < N_NODES) inv_row[c0 + 1] = (v1 > 0) ? rsqrtf((float)v1) : 0.0f;
    }
}

// ---- y0 (fp16) = inv_row (*) emb ; one half2 (2 dims) per thread, full grid ----
__global__ void init_y_kernel(const float* __restrict__ inv_row,
                              const float2* __restrict__ emb2, __half2* __restrict__ y0) {
    int i = blockIdx.x * blockDim.x + threadIdx.x;     // over N*32
    if (i < N_NODES * (EMBED_DIM / 2)) {
        float w = inv_row[i >> 5];
        float2 e = emb2[i];
        y0[i] = __floats2half2_rn(w * e.x, w * e.y);
    }
}

// ---- one wave per destination node; compact CSR; 8 edges per gather round ----
// Lane layout: e = lane>>3 (edge slot 0..7), d4 = lane&7 (16-B chunk = dims 8*d4..8*d4+7).
// One y row = 128 B = 8 int4 chunks; one load instr = 64 lanes x 16 B = 8 whole edges.
// Cross-edge reduce: 3x shfl_xor (masks 8,16,32) -> every lane holds the full d4-slice sum.
// Epilogue split: e==0 lanes write y_dst (contiguous 128-B fp16 row); e==1 lanes rmw out
// (2x float4 each). out/emb operand is loaded BEFORE the gather loop (independent).
// mode 0: y_dst = h(inv_row*v); out = emb + v
// mode 1: y_dst = h(inv_row*v); out += v
// mode 2: out = (out + v) * 0.25
__global__ void __launch_bounds__(256, 8)
layer_kernel(const int* __restrict__ packed_pc,
             const int* __restrict__ sorted_idx,
             const float* __restrict__ inv_row,
             const float* __restrict__ inv_col,
             const int4* __restrict__ y_src,
             int4* __restrict__ y_dst,
             float4* __restrict__ out4,
             const float4* __restrict__ emb4,
             int mode) {
    int wid  = (blockIdx.x * blockDim.x + threadIdx.x) >> 6;
    int lane = threadIdx.x & 63;
    if (wid >= N_NODES) return;
    int d4 = lane & 7;
    int e  = lane >> 3;
    int packed = packed_pc[wid];            // wave-uniform -> scalar load
    int cnt = packed & 127;
    int ptr = packed >> 7;
    int lidx = (cnt > 0) ? (ptr + ((lane < cnt) ? lane : 0)) : 0;
    int idx = sorted_idx[lidx];

    // hoist epilogue operand load (independent of gathers -> overlaps their latency)
    int obase = wid * 16 + d4 * 2;
    float4 o0, o1;
    if (e == 1) {
        const float4* src = (mode == 0) ? emb4 : (const float4*)out4;
        o0 = src[obase];
        o1 = src[obase + 1];
    }

    float f[8] = {0.f, 0.f, 0.f, 0.f, 0.f, 0.f, 0.f, 0.f};
    for (int j = 0; j < cnt; j += 8) {
        int s = __shfl(idx, j + e);                    // broadcast edge (j+e)'s source node
        int4 v = y_src[s * 8 + d4];                    // 16 B of that node's fp16 row
        if (j + e < cnt) {
            float2 a0 = __half22float2(*reinterpret_cast<const __half2*>(&v.x));
            float2 a1 = __half22float2(*reinterpret_cast<const __half2*>(&v.y));
            float2 a2 = __half22float2(*reinterpret_cast<const __half2*>(&v.z));
            float2 a3 = __half22float2(*reinterpret_cast<const __half2*>(&v.w));
            f[0] += a0.x; f[1] += a0.y; f[2] += a1.x; f[3] += a1.y;
            f[4] += a2.x; f[5] += a2.y; f[6] += a3.x; f[7] += a3.y;
        }
    }
    // reduce the 8 edge slots (lanes differing in bits 3..5 share d4)
#pragma unroll
    for (int k = 0; k < 8; ++k) {
        f[k] += __shfl_xor(f[k], 8);
        f[k] += __shfl_xor(f[k], 16);
        f[k] += __shfl_xor(f[k], 32);
    }
    float invc = inv_col[wid];
#pragma unroll
    for (int k = 0; k < 8; ++k) f[k] *= invc;

    if (mode != 2) {
        if (e == 0) {
            float w = inv_row[wid];
            __half2 p0 = __floats2half2_rn(w * f[0], w * f[1]);
            __half2 p1 = __floats2half2_rn(w * f[2], w * f[3]);
            __half2 p2 = __floats2half2_rn(w * f[4], w * f[5]);
            __half2 p3 = __floats2half2_rn(w * f[6], w * f[7]);
            int4 st;
            st.x = *reinterpret_cast<int*>(&p0);
            st.y = *reinterpret_cast<int*>(&p1);
            st.z = *reinterpret_cast<int*>(&p2);
            st.w = *reinterpret_cast<int*>(&p3);
            y_dst[wid * 8 + d4] = st;                 // contiguous 128-B row
        } else if (e == 1) {
            o0.x += f[0]; o0.y += f[1]; o0.z += f[2]; o0.w += f[3];
            o1.x += f[4]; o1.y += f[5]; o1.z += f[6]; o1.w += f[7];
            out4[obase]     = o0;
            out4[obase + 1] = o1;
        }
    } else if (e == 1) {
        o0.x = (o0.x + f[0]) * 0.25f; o0.y = (o0.y + f[1]) * 0.25f;
        o0.z = (o0.z + f[2]) * 0.25f; o0.w = (o0.w + f[3]) * 0.25f;
        o1.x = (o1.x + f[4]) * 0.25f; o1.y = (o1.y + f[5]) * 0.25f;
        o1.z = (o1.z + f[6]) * 0.25f; o1.w = (o1.w + f[7]) * 0.25f;
        out4[obase]     = o0;
        out4[obase + 1] = o1;
    }
}

extern "C" void kernel_launch(void* const* d_in, const int* in_sizes, int n_in,
                              void* d_out, int out_size, void* d_ws, size_t ws_size,
                              hipStream_t stream) {
    const int*   edge_index = (const int*)d_in[0];   // [2, E]
    const float* embedding  = (const float*)d_in[1]; // [N, 64]
    const int* row = edge_index;
    const int* col = edge_index + NUM_EDGES;
    float* out = (float*)d_out;

    char* ws = (char*)d_ws;
    auto align_up = [](size_t v) { return (v + 255) & ~size_t(255); };
    size_t off = 0;
    int* gcur_c     = (int*)(ws + off); off = align_up(off + sizeof(int) * NBUCK);
    int* gcur_r     = (int*)(ws + off); off = align_up(off + sizeof(int) * NBUCK);
    size_t cursor_bytes = off;                        // zero both cursor arrays in one memset
    int* packed_pc  = (int*)(ws + off); off = align_up(off + sizeof(int) * N_NODES);
    float* inv_row  = (float*)(ws + off); off = align_up(off + sizeof(float) * N_NODES);
    float* inv_col  = (float*)(ws + off); off = align_up(off + sizeof(float) * N_NODES);
    int* sorted_idx = (int*)(ws + off); off = align_up(off + sizeof(int) * NUM_EDGES);   // 4.8 MB
    __half2* ya     = (__half2*)(ws + off); off = align_up(off + sizeof(__half2) * N_NODES * 32);
    __half2* yb     = (__half2*)(ws + off); off = align_up(off + sizeof(__half2) * N_NODES * 32);
    // binned arrays alias yb (19.2 MB): consumed by pass2 before yb's first write (layer 1)
    unsigned int*   binned_c = (unsigned int*)yb;                                        // 5.25 MB
    unsigned short* binned_r = (unsigned short*)((char*)yb + align_up(sizeof(unsigned int) * NBUCK * CAPC)); // 2.63 MB

    // 1) zero the bucket cursors
    hipMemsetAsync(gcur_c, 0, cursor_bytes, stream);
    // 2) pass 1: bin edges
    pass1_bin<<<P1_BLOCKS, 256, 0, stream>>>((const int4*)row, (const int4*)col,
                                             gcur_c, gcur_r, binned_c, binned_r);
    // 3) pass 2: compact CSR + inv arrays
    pass2_place<<<2 * NBUCK, 256, 0, stream>>>(gcur_c, gcur_r, binned_c, binned_r,
                                               sorted_idx, packed_pc, inv_col, inv_row);
    // 4) y0 = fp16(inv_row (*) emb), full grid
    {
        int n2 = N_NODES * 32;
        int threads = 256, blocks = (n2 + threads - 1) / threads;
        init_y_kernel<<<blocks, threads, 0, stream>>>(inv_row, (const float2*)embedding, ya);
    }
    // 5) three gather layers (y ping-pong: ya -> yb -> ya)
    {
        int threads = 256;
        int blocks = (N_NODES * 64 + threads - 1) / threads;   // 37500
        layer_kernel<<<blocks, threads, 0, stream>>>(packed_pc, sorted_idx, inv_row, inv_col,
                                                     (const int4*)ya, (int4*)yb, (float4*)out,
                                                     (const float4*)embedding, 0);
        layer_kernel<<<blocks, threads, 0, stream>>>(packed_pc, sorted_idx, inv_row, inv_col,
                                                     (const int4*)yb, (int4*)ya, (float4*)out,
                                                     (const float4*)embedding, 1);
        layer_kernel<<<blocks, threads, 0, stream>>>(packed_pc, sorted_idx, inv_row, inv_col,
                                                     (const int4*)ya, (int4*)yb /*unused*/, (float4*)out,
                                                     (const float4*)embedding, 2);
    }
}

// Round 2
// 277.882 us; speedup vs baseline: 1.1271x; 1.1271x over previous
//
#include <hip/hip_runtime.h>
#include <hip/hip_fp16.h>

// LightGCN, atomic-free COMPACT CSR build + fp16 gather layers.
//  pass1 (293 blocks, EPB=4096): int4 edge loads, LDS bucket histograms (293 buckets of 512
//         nodes), per-(block,bucket) run reservation (~172K global atomics), scatter to bucket
//         streams. (EPB=1024 tried in r1: +14 us — 4x per-block fixed cost + 687K contended
//         cursor atomics. Reverted.)
//  pass2 (586 blocks): col-blocks: LDS hist -> scan -> compact CSR + FIXED-STRIDE inline edge
//         table (cap 16) + packed(ptr,cnt) + inv_col; row-blocks: LDS hist -> inv_row.
//         (y0 init is a separate full-grid kernel — NOT fused; fusing serialized 9.6 MB of
//         streaming through 147 blocks and cost 50 us.)
//  layers: one wave/node, 8 edges per 1-KB gather round (16 B/lane). r1 post-mortem: layers are
//         LATENCY-bound on the dependent-load chain packed -> sorted_idx -> y gather (3 serial
//         misses). fixed_idx[node*16+slot] has an address independent of packed_pc, so the index
//         load issues IN PARALLEL with packed/inv/epilogue loads -> chain depth 2. Nodes with
//         cnt>16 (~0.2%, wave-uniform branch) fall back to compact CSR.

constexpr int NUM_USERS = 100000;
constexpr int NUM_ITEMS = 50000;
constexpr int N_NODES   = NUM_USERS + NUM_ITEMS;   // 150000
constexpr int EMBED_DIM = 64;
constexpr int NUM_EDGES = 1200000;
constexpr int SHIFT = 9;                           // coarse bucket = node >> 9
constexpr int BSZ   = 1 << SHIFT;                  // 512 nodes per bucket
constexpr int NBUCK = (N_NODES + BSZ - 1) >> SHIFT;            // 293
constexpr int CAPC  = 4480;                        // bucket capacity (Poisson mean 4096, sigma 64)
constexpr int EPB   = 4096;                        // edges per pass-1 block
constexpr int P1_BLOCKS = (NUM_EDGES + EPB - 1) / EPB;         // 293
constexpr int FIXCAP = 16;                         // inline edge slots per node

// ---- pass 1: LDS-aggregated binning (int4 = 4 edges per thread-iter) ----
__global__ void __launch_bounds__(256)
pass1_bin(const int4* __restrict__ row4, const int4* __restrict__ col4,
          int* __restrict__ gcur_c, int* __restrict__ gcur_r,
          unsigned int* __restrict__ binned_c, unsigned short* __restrict__ binned_r) {
    __shared__ int hist_c[NBUCK], hist_r[NBUCK], cur_c[NBUCK], cur_r[NBUCK];
    int t = threadIdx.x;
    for (int i = t; i < NBUCK; i += 256) { hist_c[i] = 0; hist_r[i] = 0; }
    __syncthreads();
    int base4 = blockIdx.x * (EPB / 4);
    constexpr int NV = NUM_EDGES / 4;
    // phase A: per-block bucket counts
    for (int k = 0; k < EPB / 1024; ++k) {
        int v = base4 + k * 256 + t;
        if (v < NV) {
            int4 c = col4[v];
            atomicAdd(&hist_c[c.x >> SHIFT], 1);
            atomicAdd(&hist_c[c.y >> SHIFT], 1);
            atomicAdd(&hist_c[c.z >> SHIFT], 1);
            atomicAdd(&hist_c[c.w >> SHIFT], 1);
            int4 r = row4[v];
            atomicAdd(&hist_r[r.x >> SHIFT], 1);
            atomicAdd(&hist_r[r.y >> SHIFT], 1);
            atomicAdd(&hist_r[r.z >> SHIFT], 1);
            atomicAdd(&hist_r[r.w >> SHIFT], 1);
        }
    }
    __syncthreads();
    // phase B: reserve contiguous runs (one global atomic per block x bucket)
    for (int i = t; i < NBUCK; i += 256) {
        cur_c[i] = atomicAdd(&gcur_c[i], hist_c[i]);
        cur_r[i] = atomicAdd(&gcur_r[i], hist_r[i]);
    }
    __syncthreads();
    // phase C: scatter into bucket streams
    for (int k = 0; k < EPB / 1024; ++k) {
        int v = base4 + k * 256 + t;
        if (v < NV) {
            int4 c = col4[v];
            int4 r = row4[v];
            int cc[4] = {c.x, c.y, c.z, c.w};
            int rr[4] = {r.x, r.y, r.z, r.w};
#pragma unroll
            for (int q = 0; q < 4; ++q) {
                int dc = cc[q] >> SHIFT;
                int sc = atomicAdd(&cur_c[dc], 1);
                if (sc < CAPC)
                    binned_c[dc * CAPC + sc] =
                        ((unsigned)(cc[q] & (BSZ - 1)) << 18) | (unsigned)rr[q];
                int dr = rr[q] >> SHIFT;
                int sr = atomicAdd(&cur_r[dr], 1);
                if (sr < CAPC)
                    binned_r[dr * CAPC + sr] = (unsigned short)(rr[q] & (BSZ - 1));
            }
        }
    }
}

// ---- pass 2 ----
// blocks 0..292: compact CSR + fixed-stride inline table for col-bucket b + packed + inv_col
// blocks 293..585: row histogram -> inv_row
__global__ void __launch_bounds__(256)
pass2_place(const int* __restrict__ gcur_c, const int* __restrict__ gcur_r,
            const unsigned int* __restrict__ binned_c, const unsigned short* __restrict__ binned_r,
            int* __restrict__ sorted_idx, int* __restrict__ fixed_idx, int* __restrict__ packed_pc,
            float* __restrict__ inv_col, float* __restrict__ inv_row) {
    __shared__ int hist[BSZ];
    __shared__ int obase[BSZ];          // per-node start offset (pre-cursor), for within-node slot
    __shared__ int partial[256];
    int t = threadIdx.x;
    hist[t] = 0; hist[t + 256] = 0;
    __syncthreads();
    int b = blockIdx.x;
    if (b < NBUCK) {
        int n = gcur_c[b]; if (n > CAPC) n = CAPC;
        const unsigned int* src = binned_c + b * CAPC;
        // local histogram
        for (int i = t; i < n; i += 256) atomicAdd(&hist[src[i] >> 18], 1);
        // bucket base = sum of gcur_c[0..b)
        int s = 0;
        for (int i = t; i < b; i += 256) s += gcur_c[i];
        partial[t] = s;
        __syncthreads();
        for (int off = 128; off > 0; off >>= 1) {
            if (t < off) partial[t] += partial[t + off];
            __syncthreads();
        }
        int bucket_base = partial[0];
        __syncthreads();
        // exclusive scan of hist[0..511] (2 entries per thread)
        int v0 = hist[t * 2], v1 = hist[t * 2 + 1];
        int sum = v0 + v1;
        partial[t] = sum; __syncthreads();
        for (int off = 1; off < 256; off <<= 1) {
            int tv = (t >= off) ? partial[t - off] : 0;
            __syncthreads();
            partial[t] += tv;
            __syncthreads();
        }
        int excl = partial[t] - sum;
        int o0 = excl, o1 = excl + v0;
        hist[t * 2] = o0; hist[t * 2 + 1] = o1;
        obase[t * 2] = o0; obase[t * 2 + 1] = o1;
        // packed(ptr,cnt) + inv_col  (cnt < 128; ptr < 2^21)
        int c0 = (b << SHIFT) | (t * 2);
        if (c0 < N_NODES) {
            packed_pc[c0] = ((bucket_base + o0) << 7) | v0;
            inv_col[c0] = (v0 > 0) ? rsqrtf((float)v0) : 0.0f;
        }
        int c1 = c0 + 1;
        if (c1 < N_NODES) {
            packed_pc[c1] = ((bucket_base + o1) << 7) | v1;
            inv_col[c1] = (v1 > 0) ? rsqrtf((float)v1) : 0.0f;
        }
        __syncthreads();
        // compact placement via LDS cursors + fixed-stride mirror (first FIXCAP edges)
        for (int i = t; i < n; i += 256) {
            unsigned int w = src[i];
            int lc = w >> 18;
            int r  = (int)(w & 0x3FFFFu);
            int slot = atomicAdd(&hist[lc], 1);
            sorted_idx[bucket_base + slot] = r;
            int within = slot - obase[lc];
            if (within < FIXCAP)
                fixed_idx[(((b << SHIFT) | lc) << 4) + within] = r;
        }
    } else {
        int bb = b - NBUCK;
        int n = gcur_r[bb]; if (n > CAPC) n = CAPC;
        const unsigned short* src = binned_r + bb * CAPC;
        for (int i = t; i < n; i += 256) atomicAdd(&hist[src[i]], 1);
        __syncthreads();
        int c0 = (bb << SHIFT) | (t * 2);
        int v0 = hist[t * 2], v1 = hist[t * 2 + 1];
        if (c0 < N_NODES)     inv_row[c0] = (v0 > 0) ? rsqrtf((float)v0) : 0.0f;
        if (c0 + 1 < N_NODES) inv_row[c0 + 1] = (v1 > 0) ? rsqrtf((float)v1) : 0.0f;
    }
}

// ---- y0 (fp16) = inv_row (*) emb ; one float4 (4 dims) per thread, full grid ----
__global__ void init_y_kernel(const float* __restrict__ inv_row,
                              const float4* __restrict__ emb4, int2* __restrict__ y0) {
    int i = blockIdx.x * blockDim.x + threadIdx.x;     // over N*16
    if (i < N_NODES * (EMBED_DIM / 4)) {
        float w = inv_row[i >> 4];
        float4 e = emb4[i];
        __half2 h0 = __floats2half2_rn(w * e.x, w * e.y);
        __half2 h1 = __floats2half2_rn(w * e.z, w * e.w);
        y0[i] = make_int2(*reinterpret_cast<int*>(&h0), *reinterpret_cast<int*>(&h1));
    }
}

// ---- one wave per destination node; 8 edges per gather round ----
// Lane layout: e = lane>>3 (edge slot 0..7), d4 = lane&7 (16-B chunk = dims 8*d4..8*d4+7).
// Head loads all INDEPENDENT (issue concurrently): fixed_idx (addr = wid,lane only),
// packed_pc, inv_col, inv_row, epilogue out/emb operand. Chain depth = head || -> gather.
// cnt>16 (~300 nodes): wave-uniform fallback to compact CSR (adds one dependent load).
// Cross-edge reduce: 3x shfl_xor (masks 8,16,32).
// Epilogue split: e==0 lanes write y_dst (contiguous 128-B fp16 row); e==1 lanes rmw out.
// mode 0: y_dst = h(inv_row*v); out = emb + v
// mode 1: y_dst = h(inv_row*v); out += v
// mode 2: out = (out + v) * 0.25
__global__ void __launch_bounds__(256, 8)
layer_kernel(const int* __restrict__ packed_pc,
             const int* __restrict__ sorted_idx,
             const int* __restrict__ fixed_idx,
             const float* __restrict__ inv_row,
             const float* __restrict__ inv_col,
             const int4* __restrict__ y_src,
             int4* __restrict__ y_dst,
             float4* __restrict__ out4,
             const float4* __restrict__ emb4,
             int mode) {
    int wid  = (blockIdx.x * blockDim.x + threadIdx.x) >> 6;
    int lane = threadIdx.x & 63;
    if (wid >= N_NODES) return;
    int d4 = lane & 7;
    int e  = lane >> 3;

    // --- head loads, all independent ---
    int rec    = fixed_idx[(wid << 4) | (lane & 15)];   // inline slots (may be garbage >= cnt)
    int packed = packed_pc[wid];
    float invc = inv_col[wid];
    float invr = inv_row[wid];
    int obase = wid * 16 + d4 * 2;
    float4 o0, o1;
    if (e == 1) {
        const float4* src = (mode == 0) ? emb4 : (const float4*)out4;
        o0 = src[obase];
        o1 = src[obase + 1];
    }

    int cnt = packed & 127;
    int ptr = packed >> 7;
    int idx = ((lane & 15) < cnt) ? rec : 0;            // clamp garbage slots to safe node 0
    if (cnt > FIXCAP) {                                  // rare, wave-uniform
        idx = sorted_idx[ptr + ((lane < cnt) ? lane : 0)];
    }

    float f[8] = {0.f, 0.f, 0.f, 0.f, 0.f, 0.f, 0.f, 0.f};
    for (int j = 0; j < cnt; j += 8) {
        int s = __shfl(idx, j + e);                    // broadcast edge (j+e)'s source node
        int4 v = y_src[s * 8 + d4];                    // 16 B of that node's fp16 row
        if (j + e < cnt) {
            float2 a0 = __half22float2(*reinterpret_cast<const __half2*>(&v.x));
            float2 a1 = __half22float2(*reinterpret_cast<const __half2*>(&v.y));
            float2 a2 = __half22float2(*reinterpret_cast<const __half2*>(&v.z));
            float2 a3 = __half22float2(*reinterpret_cast<const __half2*>(&v.w));
            f[0] += a0.x; f[1] += a0.y; f[2] += a1.x; f[3] += a1.y;
            f[4] += a2.x; f[5] += a2.y; f[6] += a3.x; f[7] += a3.y;
        }
    }
    // reduce the 8 edge slots (lanes differing in bits 3..5 share d4)
#pragma unroll
    for (int k = 0; k < 8; ++k) {
        f[k] += __shfl_xor(f[k], 8);
        f[k] += __shfl_xor(f[k], 16);
        f[k] += __shfl_xor(f[k], 32);
    }
#pragma unroll
    for (int k = 0; k < 8; ++k) f[k] *= invc;

    if (mode != 2) {
        if (e == 0) {
            __half2 p0 = __floats2half2_rn(invr * f[0], invr * f[1]);
            __half2 p1 = __floats2half2_rn(invr * f[2], invr * f[3]);
            __half2 p2 = __floats2half2_rn(invr * f[4], invr * f[5]);
            __half2 p3 = __floats2half2_rn(invr * f[6], invr * f[7]);
            int4 st;
            st.x = *reinterpret_cast<int*>(&p0);
            st.y = *reinterpret_cast<int*>(&p1);
            st.z = *reinterpret_cast<int*>(&p2);
            st.w = *reinterpret_cast<int*>(&p3);
            y_dst[wid * 8 + d4] = st;                 // contiguous 128-B row
        } else if (e == 1) {
            o0.x += f[0]; o0.y += f[1]; o0.z += f[2]; o0.w += f[3];
            o1.x += f[4]; o1.y += f[5]; o1.z += f[6]; o1.w += f[7];
            out4[obase]     = o0;
            out4[obase + 1] = o1;
        }
    } else if (e == 1) {
        o0.x = (o0.x + f[0]) * 0.25f; o0.y = (o0.y + f[1]) * 0.25f;
        o0.z = (o0.z + f[2]) * 0.25f; o0.w = (o0.w + f[3]) * 0.25f;
        o1.x = (o1.x + f[4]) * 0.25f; o1.y = (o1.y + f[5]) * 0.25f;
        o1.z = (o1.z + f[6]) * 0.25f; o1.w = (o1.w + f[7]) * 0.25f;
        out4[obase]     = o0;
        out4[obase + 1] = o1;
    }
}

extern "C" void kernel_launch(void* const* d_in, const int* in_sizes, int n_in,
                              void* d_out, int out_size, void* d_ws, size_t ws_size,
                              hipStream_t stream) {
    const int*   edge_index = (const int*)d_in[0];   // [2, E]
    const float* embedding  = (const float*)d_in[1]; // [N, 64]
    const int* row = edge_index;
    const int* col = edge_index + NUM_EDGES;
    float* out = (float*)d_out;

    char* ws = (char*)d_ws;
    auto align_up = [](size_t v) { return (v + 255) & ~size_t(255); };
    size_t off = 0;
    int* gcur_c     = (int*)(ws + off); off = align_up(off + sizeof(int) * NBUCK);
    int* gcur_r     = (int*)(ws + off); off = align_up(off + sizeof(int) * NBUCK);
    size_t cursor_bytes = off;                        // zero both cursor arrays in one memset
    int* packed_pc  = (int*)(ws + off); off = align_up(off + sizeof(int) * N_NODES);
    float* inv_row  = (float*)(ws + off); off = align_up(off + sizeof(float) * N_NODES);
    float* inv_col  = (float*)(ws + off); off = align_up(off + sizeof(float) * N_NODES);
    int* sorted_idx = (int*)(ws + off); off = align_up(off + sizeof(int) * NUM_EDGES);   // 4.8 MB
    int* fixed_idx  = (int*)(ws + off); off = align_up(off + sizeof(int) * N_NODES * FIXCAP); // 9.6 MB
    __half2* ya     = (__half2*)(ws + off); off = align_up(off + sizeof(__half2) * N_NODES * 32);
    __half2* yb     = (__half2*)(ws + off); off = align_up(off + sizeof(__half2) * N_NODES * 32);
    // binned arrays alias yb (19.2 MB): consumed by pass2 before yb's first write (layer 1)
    unsigned int*   binned_c = (unsigned int*)yb;                                        // 5.25 MB
    unsigned short* binned_r = (unsigned short*)((char*)yb + align_up(sizeof(unsigned int) * NBUCK * CAPC)); // 2.63 MB

    // 1) zero the bucket cursors
    hipMemsetAsync(gcur_c, 0, cursor_bytes, stream);
    // 2) pass 1: bin edges
    pass1_bin<<<P1_BLOCKS, 256, 0, stream>>>((const int4*)row, (const int4*)col,
                                             gcur_c, gcur_r, binned_c, binned_r);
    // 3) pass 2: compact CSR + fixed-stride table + inv arrays
    pass2_place<<<2 * NBUCK, 256, 0, stream>>>(gcur_c, gcur_r, binned_c, binned_r,
                                               sorted_idx, fixed_idx, packed_pc, inv_col, inv_row);
    // 4) y0 = fp16(inv_row (*) emb), full grid, float4 loads
    {
        int n4 = N_NODES * 16;
        int threads = 256, blocks = (n4 + threads - 1) / threads;
        init_y_kernel<<<blocks, threads, 0, stream>>>(inv_row, (const float4*)embedding, (int2*)ya);
    }
    // 5) three gather layers (y ping-pong: ya -> yb -> ya)
    {
        int threads = 256;
        int blocks = (N_NODES * 64 + threads - 1) / threads;   // 37500
        layer_kernel<<<blocks, threads, 0, stream>>>(packed_pc, sorted_idx, fixed_idx, inv_row, inv_col,
                                                     (const int4*)ya, (int4*)yb, (float4*)out,
                                                     (const float4*)embedding, 0);
        layer_kernel<<<blocks, threads, 0, stream>>>(packed_pc, sorted_idx, fixed_idx, inv_row, inv_col,
                                                     (const int4*)yb, (int4*)ya, (float4*)out,
                                                     (const float4*)embedding, 1);
        layer_kernel<<<blocks, threads, 0, stream>>>(packed_pc, sorted_idx, fixed_idx, inv_row, inv_col,
                                                     (const int4*)ya, (int4*)yb /*unused*/, (float4*)out,
                                                     (const float4*)embedding, 2);
    }
}

// Round 4
// 271.930 us; speedup vs baseline: 1.1518x; 1.0219x over previous
//
#include <hip/hip_runtime.h>
#include <hip/hip_fp16.h>

// LightGCN, atomic-free COMPACT CSR build + fp16 gather layers.
//  pass1 (293 blocks x 1024 thr): int4 edge loads, LDS bucket histograms (293 buckets of 512
//         nodes), per-(block,bucket) run reservation (~172K global atomics), scatter to bucket
//         streams. 1024 thr/block: 16 waves/CU vs 4 (r2 was ~1.2 waves/SIMD, latency-starved);
//         same block count & global-atomic count (r1's EPB=1024 split regressed +14 us).
//  pass2 (586 blocks): col-blocks: LDS hist -> scan -> compact CSR + FIXED-STRIDE inline edge
//         table (cap 16) + packed(ptr,cnt) + inv_col; row-blocks: LDS hist -> inv_row.
//         (y0 init is a separate full-grid kernel — NOT fused; fusing serialized 9.6 MB of
//         streaming through 147 blocks and cost 50 us.)
//  layers: one wave/node, 16 B/lane gathers (8 edges per 1-KB load). r2 post-mortem: the
//         runtime-trip gather loop serialized rounds (load->waitcnt->accum->branch), so cnt>8
//         nodes (~41%) paid 2 SERIAL ~700-cy latencies. cnt<=16 fast path (99.8% of nodes,
//         wave-uniform branch) issues BOTH gather loads before either waitcnt -> 2 KB in
//         flight, serial depth = head || -> gather. cnt>16 falls back to compact CSR loop.
//  (r3 bench was an infra failure — container never ran; source resubmitted unchanged.)

constexpr int NUM_USERS = 100000;
constexpr int NUM_ITEMS = 50000;
constexpr int N_NODES   = NUM_USERS + NUM_ITEMS;   // 150000
constexpr int EMBED_DIM = 64;
constexpr int NUM_EDGES = 1200000;
constexpr int SHIFT = 9;                           // coarse bucket = node >> 9
constexpr int BSZ   = 1 << SHIFT;                  // 512 nodes per bucket
constexpr int NBUCK = (N_NODES + BSZ - 1) >> SHIFT;            // 293
constexpr int CAPC  = 4480;                        // bucket capacity (Poisson mean 4096, sigma 64)
constexpr int EPB   = 4096;                        // edges per pass-1 block
constexpr int P1_BLOCKS = (NUM_EDGES + EPB - 1) / EPB;         // 293
constexpr int FIXCAP = 16;                         // inline edge slots per node

// ---- pass 1: LDS-aggregated binning, 1024 threads (1 int4 = 4 edges per thread) ----
__global__ void __launch_bounds__(1024)
pass1_bin(const int4* __restrict__ row4, const int4* __restrict__ col4,
          int* __restrict__ gcur_c, int* __restrict__ gcur_r,
          unsigned int* __restrict__ binned_c, unsigned short* __restrict__ binned_r) {
    __shared__ int hist_c[NBUCK], hist_r[NBUCK], cur_c[NBUCK], cur_r[NBUCK];
    int t = threadIdx.x;
    for (int i = t; i < NBUCK; i += 1024) { hist_c[i] = 0; hist_r[i] = 0; }
    __syncthreads();
    int base4 = blockIdx.x * (EPB / 4);
    constexpr int NV = NUM_EDGES / 4;
    int v = base4 + t;
    int4 c, r;
    bool valid = (v < NV);
    // phase A: per-block bucket counts
    if (valid) {
        c = col4[v];
        r = row4[v];
        atomicAdd(&hist_c[c.x >> SHIFT], 1);
        atomicAdd(&hist_c[c.y >> SHIFT], 1);
        atomicAdd(&hist_c[c.z >> SHIFT], 1);
        atomicAdd(&hist_c[c.w >> SHIFT], 1);
        atomicAdd(&hist_r[r.x >> SHIFT], 1);
        atomicAdd(&hist_r[r.y >> SHIFT], 1);
        atomicAdd(&hist_r[r.z >> SHIFT], 1);
        atomicAdd(&hist_r[r.w >> SHIFT], 1);
    }
    __syncthreads();
    // phase B: reserve contiguous runs (one global atomic per block x bucket)
    for (int i = t; i < NBUCK; i += 1024) {
        cur_c[i] = atomicAdd(&gcur_c[i], hist_c[i]);
        cur_r[i] = atomicAdd(&gcur_r[i], hist_r[i]);
    }
    __syncthreads();
    // phase C: scatter into bucket streams
    if (valid) {
        int cc[4] = {c.x, c.y, c.z, c.w};
        int rr[4] = {r.x, r.y, r.z, r.w};
#pragma unroll
        for (int q = 0; q < 4; ++q) {
            int dc = cc[q] >> SHIFT;
            int sc = atomicAdd(&cur_c[dc], 1);
            if (sc < CAPC)
                binned_c[dc * CAPC + sc] =
                    ((unsigned)(cc[q] & (BSZ - 1)) << 18) | (unsigned)rr[q];
            int dr = rr[q] >> SHIFT;
            int sr = atomicAdd(&cur_r[dr], 1);
            if (sr < CAPC)
                binned_r[dr * CAPC + sr] = (unsigned short)(rr[q] & (BSZ - 1));
        }
    }
}

// ---- pass 2 ----
// blocks 0..292: compact CSR + fixed-stride inline table for col-bucket b + packed + inv_col
// blocks 293..585: row histogram -> inv_row
__global__ void __launch_bounds__(256)
pass2_place(const int* __restrict__ gcur_c, const int* __restrict__ gcur_r,
            const unsigned int* __restrict__ binned_c, const unsigned short* __restrict__ binned_r,
            int* __restrict__ sorted_idx, int* __restrict__ fixed_idx, int* __restrict__ packed_pc,
            float* __restrict__ inv_col, float* __restrict__ inv_row) {
    __shared__ int hist[BSZ];
    __shared__ int obase[BSZ];          // per-node start offset (pre-cursor), for within-node slot
    __shared__ int partial[256];
    int t = threadIdx.x;
    hist[t] = 0; hist[t + 256] = 0;
    __syncthreads();
    int b = blockIdx.x;
    if (b < NBUCK) {
        int n = gcur_c[b]; if (n > CAPC) n = CAPC;
        const unsigned int* src = binned_c + b * CAPC;
        // local histogram
        for (int i = t; i < n; i += 256) atomicAdd(&hist[src[i] >> 18], 1);
        // bucket base = sum of gcur_c[0..b)
        int s = 0;
        for (int i = t; i < b; i += 256) s += gcur_c[i];
        partial[t] = s;
        __syncthreads();
        for (int off = 128; off > 0; off >>= 1) {
            if (t < off) partial[t] += partial[t + off];
            __syncthreads();
        }
        int bucket_base = partial[0];
        __syncthreads();
        // exclusive scan of hist[0..511] (2 entries per thread)
        int v0 = hist[t * 2], v1 = hist[t * 2 + 1];
        int sum = v0 + v1;
        partial[t] = sum; __syncthreads();
        for (int off = 1; off < 256; off <<= 1) {
            int tv = (t >= off) ? partial[t - off] : 0;
            __syncthreads();
            partial[t] += tv;
            __syncthreads();
        }
        int excl = partial[t] - sum;
        int o0 = excl, o1 = excl + v0;
        hist[t * 2] = o0; hist[t * 2 + 1] = o1;
        obase[t * 2] = o0; obase[t * 2 + 1] = o1;
        // packed(ptr,cnt) + inv_col  (cnt < 128; ptr < 2^21)
        int c0 = (b << SHIFT) | (t * 2);
        if (c0 < N_NODES) {
            packed_pc[c0] = ((bucket_base + o0) << 7) | v0;
            inv_col[c0] = (v0 > 0) ? rsqrtf((float)v0) : 0.0f;
        }
        int c1 = c0 + 1;
        if (c1 < N_NODES) {
            packed_pc[c1] = ((bucket_base + o1) << 7) | v1;
            inv_col[c1] = (v1 > 0) ? rsqrtf((float)v1) : 0.0f;
        }
        __syncthreads();
        // compact placement via LDS cursors + fixed-stride mirror (first FIXCAP edges)
        for (int i = t; i < n; i += 256) {
            unsigned int w = src[i];
            int lc = w >> 18;
            int r  = (int)(w & 0x3FFFFu);
            int slot = atomicAdd(&hist[lc], 1);
            sorted_idx[bucket_base + slot] = r;
            int within = slot - obase[lc];
            if (within < FIXCAP)
                fixed_idx[(((b << SHIFT) | lc) << 4) + within] = r;
        }
    } else {
        int bb = b - NBUCK;
        int n = gcur_r[bb]; if (n > CAPC) n = CAPC;
        const unsigned short* src = binned_r + bb * CAPC;
        for (int i = t; i < n; i += 256) atomicAdd(&hist[src[i]], 1);
        __syncthreads();
        int c0 = (bb << SHIFT) | (t * 2);
        int v0 = hist[t * 2], v1 = hist[t * 2 + 1];
        if (c0 < N_NODES)     inv_row[c0] = (v0 > 0) ? rsqrtf((float)v0) : 0.0f;
        if (c0 + 1 < N_NODES) inv_row[c0 + 1] = (v1 > 0) ? rsqrtf((float)v1) : 0.0f;
    }
}

// ---- y0 (fp16) = inv_row (*) emb ; one float4 (4 dims) per thread, full grid ----
__global__ void init_y_kernel(const float* __restrict__ inv_row,
                              const float4* __restrict__ emb4, int2* __restrict__ y0) {
    int i = blockIdx.x * blockDim.x + threadIdx.x;     // over N*16
    if (i < N_NODES * (EMBED_DIM / 4)) {
        float w = inv_row[i >> 4];
        float4 e = emb4[i];
        __half2 h0 = __floats2half2_rn(w * e.x, w * e.y);
        __half2 h1 = __floats2half2_rn(w * e.z, w * e.w);
        y0[i] = make_int2(*reinterpret_cast<int*>(&h0), *reinterpret_cast<int*>(&h1));
    }
}

// ---- one wave per destination node; 8 edges per 1-KB gather ----
// Lane layout: e = lane>>3 (edge slot 0..7), d4 = lane&7 (16-B chunk = dims 8*d4..8*d4+7).
// Head loads all INDEPENDENT (issue concurrently): fixed_idx (addr = wid,lane only),
// packed_pc, inv_col, inv_row, epilogue out/emb operand.
// cnt<=16 fast path (99.8%, wave-uniform): BOTH gather loads issued before either waitcnt.
// cnt>16 (~300 nodes): wave-uniform fallback to compact CSR loop.
// Cross-edge reduce: 3x shfl_xor (masks 8,16,32).
// Epilogue split: e==0 lanes write y_dst (contiguous 128-B fp16 row); e==1 lanes rmw out.
// mode 0: y_dst = h(inv_row*v); out = emb + v
// mode 1: y_dst = h(inv_row*v); out += v
// mode 2: out = (out + v) * 0.25
__global__ void __launch_bounds__(256, 8)
layer_kernel(const int* __restrict__ packed_pc,
             const int* __restrict__ sorted_idx,
             const int* __restrict__ fixed_idx,
             const float* __restrict__ inv_row,
             const float* __restrict__ inv_col,
             const int4* __restrict__ y_src,
             int4* __restrict__ y_dst,
             float4* __restrict__ out4,
             const float4* __restrict__ emb4,
             int mode) {
    int wid  = (blockIdx.x * blockDim.x + threadIdx.x) >> 6;
    int lane = threadIdx.x & 63;
    if (wid >= N_NODES) return;
    int d4 = lane & 7;
    int e  = lane >> 3;

    // --- head loads, all independent ---
    int rec    = fixed_idx[(wid << 4) | (lane & 15)];   // inline slots (may be garbage >= cnt)
    int packed = packed_pc[wid];
    float invc = inv_col[wid];
    float invr = inv_row[wid];
    int obase = wid * 16 + d4 * 2;
    float4 o0, o1;
    if (e == 1) {
        const float4* src = (mode == 0) ? emb4 : (const float4*)out4;
        o0 = src[obase];
        o1 = src[obase + 1];
    }

    int cnt = packed & 127;
    int ptr = packed >> 7;
    int idx = ((lane & 15) < cnt) ? rec : 0;            // clamp garbage slots to safe node 0

    float f[8] = {0.f, 0.f, 0.f, 0.f, 0.f, 0.f, 0.f, 0.f};
    if (cnt <= FIXCAP) {                                 // fast path, wave-uniform
        int s0 = __shfl(idx, e);
        int s1 = __shfl(idx, 8 + e);
        int4 va = y_src[s0 * 8 + d4];                   // both loads in flight before
        int4 vb = y_src[s1 * 8 + d4];                   // either result is consumed
        if (e < cnt) {
            float2 a0 = __half22float2(*reinterpret_cast<const __half2*>(&va.x));
            float2 a1 = __half22float2(*reinterpret_cast<const __half2*>(&va.y));
            float2 a2 = __half22float2(*reinterpret_cast<const __half2*>(&va.z));
            float2 a3 = __half22float2(*reinterpret_cast<const __half2*>(&va.w));
            f[0] += a0.x; f[1] += a0.y; f[2] += a1.x; f[3] += a1.y;
            f[4] += a2.x; f[5] += a2.y; f[6] += a3.x; f[7] += a3.y;
        }
        if (8 + e < cnt) {
            float2 a0 = __half22float2(*reinterpret_cast<const __half2*>(&vb.x));
            float2 a1 = __half22float2(*reinterpret_cast<const __half2*>(&vb.y));
            float2 a2 = __half22float2(*reinterpret_cast<const __half2*>(&vb.z));
            float2 a3 = __half22float2(*reinterpret_cast<const __half2*>(&vb.w));
            f[0] += a0.x; f[1] += a0.y; f[2] += a1.x; f[3] += a1.y;
            f[4] += a2.x; f[5] += a2.y; f[6] += a3.x; f[7] += a3.y;
        }
    } else {                                             // rare overflow path
        int sidx = sorted_idx[ptr + ((lane < cnt) ? lane : 0)];
        for (int j = 0; j < cnt; j += 8) {
            int s = __shfl(sidx, j + e);
            int4 v = y_src[s * 8 + d4];
            if (j + e < cnt) {
                float2 a0 = __half22float2(*reinterpret_cast<const __half2*>(&v.x));
                float2 a1 = __half22float2(*reinterpret_cast<const __half2*>(&v.y));
                float2 a2 = __half22float2(*reinterpret_cast<const __half2*>(&v.z));
                float2 a3 = __half22float2(*reinterpret_cast<const __half2*>(&v.w));
                f[0] += a0.x; f[1] += a0.y; f[2] += a1.x; f[3] += a1.y;
                f[4] += a2.x; f[5] += a2.y; f[6] += a3.x; f[7] += a3.y;
            }
        }
    }
    // reduce the 8 edge slots (lanes differing in bits 3..5 share d4)
#pragma unroll
    for (int k = 0; k < 8; ++k) {
        f[k] += __shfl_xor(f[k], 8);
        f[k] += __shfl_xor(f[k], 16);
        f[k] += __shfl_xor(f[k], 32);
    }
#pragma unroll
    for (int k = 0; k < 8; ++k) f[k] *= invc;

    if (mode != 2) {
        if (e == 0) {
            __half2 p0 = __floats2half2_rn(invr * f[0], invr * f[1]);
            __half2 p1 = __floats2half2_rn(invr * f[2], invr * f[3]);
            __half2 p2 = __floats2half2_rn(invr * f[4], invr * f[5]);
            __half2 p3 = __floats2half2_rn(invr * f[6], invr * f[7]);
            int4 st;
            st.x = *reinterpret_cast<int*>(&p0);
            st.y = *reinterpret_cast<int*>(&p1);
            st.z = *reinterpret_cast<int*>(&p2);
            st.w = *reinterpret_cast<int*>(&p3);
            y_dst[wid * 8 + d4] = st;                 // contiguous 128-B row
        } else if (e == 1) {
            o0.x += f[0]; o0.y += f[1]; o0.z += f[2]; o0.w += f[3];
            o1.x += f[4]; o1.y += f[5]; o1.z += f[6]; o1.w += f[7];
            out4[obase]     = o0;
            out4[obase + 1] = o1;
        }
    } else if (e == 1) {
        o0.x = (o0.x + f[0]) * 0.25f; o0.y = (o0.y + f[1]) * 0.25f;
        o0.z = (o0.z + f[2]) * 0.25f; o0.w = (o0.w + f[3]) * 0.25f;
        o1.x = (o1.x + f[4]) * 0.25f; o1.y = (o1.y + f[5]) * 0.25f;
        o1.z = (o1.z + f[6]) * 0.25f; o1.w = (o1.w + f[7]) * 0.25f;
        out4[obase]     = o0;
        out4[obase + 1] = o1;
    }
}

extern "C" void kernel_launch(void* const* d_in, const int* in_sizes, int n_in,
                              void* d_out, int out_size, void* d_ws, size_t ws_size,
                              hipStream_t stream) {
    const int*   edge_index = (const int*)d_in[0];   // [2, E]
    const float* embedding  = (const float*)d_in[1]; // [N, 64]
    const int* row = edge_index;
    const int* col = edge_index + NUM_EDGES;
    float* out = (float*)d_out;

    char* ws = (char*)d_ws;
    auto align_up = [](size_t v) { return (v + 255) & ~size_t(255); };
    size_t off = 0;
    int* gcur_c     = (int*)(ws + off); off = align_up(off + sizeof(int) * NBUCK);
    int* gcur_r     = (int*)(ws + off); off = align_up(off + sizeof(int) * NBUCK);
    size_t cursor_bytes = off;                        // zero both cursor arrays in one memset
    int* packed_pc  = (int*)(ws + off); off = align_up(off + sizeof(int) * N_NODES);
    float* inv_row  = (float*)(ws + off); off = align_up(off + sizeof(float) * N_NODES);
    float* inv_col  = (float*)(ws + off); off = align_up(off + sizeof(float) * N_NODES);
    int* sorted_idx = (int*)(ws + off); off = align_up(off + sizeof(int) * NUM_EDGES);   // 4.8 MB
    int* fixed_idx  = (int*)(ws + off); off = align_up(off + sizeof(int) * N_NODES * FIXCAP); // 9.6 MB
    __half2* ya     = (__half2*)(ws + off); off = align_up(off + sizeof(__half2) * N_NODES * 32);
    __half2* yb     = (__half2*)(ws + off); off = align_up(off + sizeof(__half2) * N_NODES * 32);
    // binned arrays alias yb (19.2 MB): consumed by pass2 before yb's first write (layer 1)
    unsigned int*   binned_c = (unsigned int*)yb;                                        // 5.25 MB
    unsigned short* binned_r = (unsigned short*)((char*)yb + align_up(sizeof(unsigned int) * NBUCK * CAPC)); // 2.63 MB

    // 1) zero the bucket cursors
    hipMemsetAsync(gcur_c, 0, cursor_bytes, stream);
    // 2) pass 1: bin edges (1024 threads/block)
    pass1_bin<<<P1_BLOCKS, 1024, 0, stream>>>((const int4*)row, (const int4*)col,
                                              gcur_c, gcur_r, binned_c, binned_r);
    // 3) pass 2: compact CSR + fixed-stride table + inv arrays
    pass2_place<<<2 * NBUCK, 256, 0, stream>>>(gcur_c, gcur_r, binned_c, binned_r,
                                               sorted_idx, fixed_idx, packed_pc, inv_col, inv_row);
    // 4) y0 = fp16(inv_row (*) emb), full grid, float4 loads
    {
        int n4 = N_NODES * 16;
        int threads = 256, blocks = (n4 + threads - 1) / threads;
        init_y_kernel<<<blocks, threads, 0, stream>>>(inv_row, (const float4*)embedding, (int2*)ya);
    }
    // 5) three gather layers (y ping-pong: ya -> yb -> ya)
    {
        int threads = 256;
        int blocks = (N_NODES * 64 + threads - 1) / threads;   // 37500
        layer_kernel<<<blocks, threads, 0, stream>>>(packed_pc, sorted_idx, fixed_idx, inv_row, inv_col,
                                                     (const int4*)ya, (int4*)yb, (float4*)out,
                                                     (const float4*)embedding, 0);
        layer_kernel<<<blocks, threads, 0, stream>>>(packed_pc, sorted_idx, fixed_idx, inv_row, inv_col,
                                                     (const int4*)yb, (int4*)ya, (float4*)out,
                                                     (const float4*)embedding, 1);
        layer_kernel<<<blocks, threads, 0, stream>>>(packed_pc, sorted_idx, fixed_idx, inv_row, inv_col,
                                                     (const int4*)ya, (int4*)yb /*unused*/, (float4*)out,
                                                     (const float4*)embedding, 2);
    }
}